// Round 11
// baseline (611.052 us; speedup 1.0000x reference)
//
#include <hip/hip_runtime.h>

#define Bn   32
#define QL   32
#define DOCn 2048
#define Sn   64
#define En   300
#define Hn   256

typedef short bf16x8 __attribute__((ext_vector_type(8)));
typedef short s16x4  __attribute__((ext_vector_type(4)));
typedef float f32x4  __attribute__((ext_vector_type(4)));

static __device__ __forceinline__ float b2f(short s){
  unsigned int u = ((unsigned int)(unsigned short)s) << 16;
  float f; __builtin_memcpy(&f, &u, 4); return f;
}
static __device__ __forceinline__ short f2b(float f){
  unsigned int u; __builtin_memcpy(&u, &f, 4);
  u = u + 0x7fffu + ((u >> 16) & 1u);
  return (short)(u >> 16);
}
static __device__ __forceinline__ float sigm(float x){ return 1.0f/(1.0f+__expf(-x)); }
static __device__ __forceinline__ float tanhx(float x){ return 1.0f - 2.0f/(__expf(2.0f*x)+1.0f); }
static __device__ __forceinline__ f32x4 mfma16(bf16x8 a, bf16x8 b, f32x4 c){
  return __builtin_amdgcn_mfma_f32_16x16x32_bf16(a, b, c, 0, 0, 0);
}
// barrier that drains LDS only (no vmcnt(0) store/load drain like __syncthreads)
static __device__ __forceinline__ void bar_lgkm(){
  asm volatile("s_waitcnt lgkmcnt(0)\n\ts_barrier" ::: "memory");
}

// ------------------------------------------------- facts + weight convert --
// Blocks 0..2047: per-(b,s) fact mean-pooling into 320-col zero-padded plane.
// Blocks 2048..2335: fp32->bf16 wih conversion (8 rows each, z-order f,b,q).
// Block 2048 also zeroes the k_gru exchange flags (stream-ordered before
// k_gru; re-zeroed every rep). Also emits num_facts (s==0, ballot).
__global__ __launch_bounds__(256) void k_facts(
    const int* __restrict__ docs, const int* __restrict__ slens,
    const float* __restrict__ emb,
    const float* __restrict__ f_wih, const float* __restrict__ b_wih,
    const float* __restrict__ q_wih,
    short* __restrict__ facts, short* __restrict__ wcvt,
    int* __restrict__ flags, float* __restrict__ dout)
{
  const int tid = threadIdx.x;

  if (blockIdx.x >= 2048){
    if (blockIdx.x == 2048 && tid < 12) flags[tid] = 0;   // exchange flags
    // ------------------------------------------------------- weight cvt ----
    const int rg0 = (blockIdx.x - 2048)*8;          // 8 rows per block
#pragma unroll
    for (int rr = 0; rr < 8; ++rr){
      const int rg = rg0 + rr;                      // 0..2303
      const int z = rg / 768, g = rg % 768;
      const float* src = ((z == 0) ? f_wih : (z == 1) ? b_wih : q_wih) + (long)g*En;
      short* dst = wcvt + (long)rg*320;
      for (int c = tid; c < 320; c += 256)
        dst[c] = (c < En) ? f2b(src[c]) : (short)0;
    }
    return;
  }

  // ---------------------------------------------------------------- facts --
  __shared__ int pref[2*Sn];
  const int blk = blockIdx.x;
  const int b = blk >> 6, s = blk & 63;
  if (tid < Sn){                       // wave 0: parallel prefix over lens
    const int v = slens[b*Sn + tid];
    int x = v;
#pragma unroll
    for (int d = 1; d < 64; d <<= 1){
      const int y = __shfl_up(x, d, 64);
      if (tid >= d) x += y;
    }
    pref[tid] = x - v;                 // exclusive prefix
    pref[Sn + tid] = v;
    if (s == 0){                       // num_facts once per b
      const unsigned long long m = __ballot(v > 0);
      if (tid == 0) dout[Bn*Hn + (long)Bn*Sn*Hn + b] = (float)__popcll(m);
    }
  }
  __syncthreads();
  const int off = pref[s];
  const int len = pref[Sn + s];
  const bool act = tid < 150;
  float a0 = 0.f, a1 = 0.f, b0 = 0.f, b1 = 0.f;
  const int* dtok = docs + b*DOCn + off;
  int tkA = (0 < len) ? dtok[0] : 0;
  int tkB = (1 < len) ? dtok[1] : 0;
  int i = 0;
  for (; i + 2 <= len; i += 2){
    const int tkA2 = (i+2 < len) ? dtok[i+2] : 0;
    const int tkB2 = (i+3 < len) ? dtok[i+3] : 0;
    if (act){
      const float2 va = *(const float2*)(emb + (long)tkA*En + 2*tid);
      const float2 vb = *(const float2*)(emb + (long)tkB*En + 2*tid);
      a0 += va.x; a1 += va.y; b0 += vb.x; b1 += vb.y;
    }
    tkA = tkA2; tkB = tkB2;
  }
  if (i < len && act){
    const float2 va = *(const float2*)(emb + (long)tkA*En + 2*tid);
    a0 += va.x; a1 += va.y;
  }
  a0 += b0; a1 += b1;
  const float inv = 1.0f / (float)(len > 0 ? len : 1);
  short* frow = facts + ((long)b*Sn + s)*320;        // 320-col padded plane
  if (act){
    frow[2*tid]   = f2b(a0*inv);
    frow[2*tid+1] = f2b(a1*inv);
  } else if (tid < 160){
    const int e = tid - 150;
    frow[300 + 2*e] = 0; frow[301 + 2*e] = 0;        // zero pad 300..319
  }
}

// -------------------------------------------------------- unified xg GEMM --
// UNCHANGED from round 8/10 (validated). 128-row tiles; tid-ordered output
// plane [t][2048 slots][16 shorts]; bhh folded for r,z gates.
__global__ __launch_bounds__(256) void k_xg(
    const short* __restrict__ facts, const short* __restrict__ wcvt,
    const int* __restrict__ queries, const float* __restrict__ emb,
    const float* __restrict__ q_bih, const float* __restrict__ q_bhh,
    const float* __restrict__ f_bih, const float* __restrict__ f_bhh,
    const float* __restrict__ b_bih, const float* __restrict__ b_bhh,
    short* __restrict__ q_xgi, short* __restrict__ f_xgi,
    short* __restrict__ b_xgi)
{
  const int z = blockIdx.z;
  const int bm = blockIdx.x, bn = blockIdx.y;
  const bool isq = (z == 2);
  if (isq && bm >= 8) return;          // q has 1024 rows only

  const float* bih = (z == 0) ? f_bih : (z == 1) ? b_bih : q_bih;
  const float* bhh = (z == 0) ? f_bhh : (z == 1) ? b_bhh : q_bhh;
  short*       xgi = (z == 0) ? f_xgi : (z == 1) ? b_xgi : q_xgi;

  __shared__ alignas(16) short Al[2][128][40];
  const int tid = threadIdx.x;
  const int l = tid & 63, w = tid >> 6;
  const int wm = w & 1, wn = w >> 1;
  const int l15 = l & 15, lq = l >> 4;
  const int ak8 = w*8;

  bf16x8 bfr[2][10];
#pragma unroll
  for (int nt = 0; nt < 2; ++nt){
    const int g = bn*64 + wn*32 + nt*16 + l15;
    const short* wr = wcvt + ((long)z*768 + g)*320;
#pragma unroll
    for (int kk = 0; kk < 10; ++kk)
      bfr[nt][kk] = *(const bf16x8*)&wr[kk*32 + lq*8];
  }

  const short* asrc_f0 = nullptr; const short* asrc_f1 = nullptr;
  const float* asrc_q0 = nullptr; const float* asrc_q1 = nullptr;
  if (isq){
    asrc_q0 = emb + (long)queries[bm*128 + l]*En;
    asrc_q1 = emb + (long)queries[bm*128 + 64 + l]*En;
  } else {
    asrc_f0 = facts + (long)(bm*128 + l)*320;
    asrc_f1 = facts + (long)(bm*128 + 64 + l)*320;
  }

  bf16x8 va0, va1;
#define LDA_(KK) do{ const int k0_ = (KK)*32 + ak8; \
    if (!isq){ \
      va0 = *(const bf16x8*)(asrc_f0 + k0_); \
      va1 = *(const bf16x8*)(asrc_f1 + k0_); \
    } else if (k0_ + 7 < En){ \
      const f32x4 p0 = *(const f32x4*)(asrc_q0+k0_), p1 = *(const f32x4*)(asrc_q0+k0_+4); \
      const f32x4 p2 = *(const f32x4*)(asrc_q1+k0_), p3 = *(const f32x4*)(asrc_q1+k0_+4); \
      _Pragma("unroll") for (int j = 0; j < 4; ++j){ \
        va0[j] = f2b(p0[j]); va0[4+j] = f2b(p1[j]); \
        va1[j] = f2b(p2[j]); va1[4+j] = f2b(p3[j]); } \
    } else { \
      _Pragma("unroll") for (int j = 0; j < 8; ++j){ const int k_ = k0_ + j; \
        va0[j] = (k_ < En) ? f2b(asrc_q0[k_]) : (short)0; \
        va1[j] = (k_ < En) ? f2b(asrc_q1[k_]) : (short)0; } \
    } }while(0)
#define STA_(BUF) do{ *(bf16x8*)&Al[BUF][l][ak8] = va0; \
    *(bf16x8*)&Al[BUF][64 + l][ak8] = va1; }while(0)

  LDA_(0); STA_(0);
  __syncthreads();

  f32x4 acc[4][2] = {};
#pragma unroll
  for (int kk = 0; kk < 10; ++kk){
    if (kk < 9) LDA_(kk+1);
#pragma unroll
    for (int mt = 0; mt < 4; ++mt){
      bf16x8 a = *(const bf16x8*)&Al[kk&1][wm*64 + mt*16 + l15][lq*8];
      acc[mt][0] = mfma16(a, bfr[0][kk], acc[mt][0]);
      acc[mt][1] = mfma16(a, bfr[1][kk], acc[mt][1]);
    }
    if (kk < 9) STA_((kk+1)&1);
    __syncthreads();
  }
#undef LDA_
#undef STA_

#pragma unroll
  for (int nt = 0; nt < 2; ++nt){
    const int cg = bn*64 + wn*32 + nt*16 + l15;   // 0..767
    float bias = bih[cg];
    if (cg < 512) bias += bhh[cg];                // fold bhh for r,z gates
    const int gate = cg >> 8, hc = cg & 255;
    const int wslot = (hc >> 4)*64 + (hc & 15);   // consumer w'*64 + l15'
#pragma unroll
    for (int mt = 0; mt < 4; ++mt){
      const int r0 = bm*128 + wm*64 + mt*16 + lq*4;
#pragma unroll
      for (int p = 0; p < 4; ++p){
        const int r = r0 + p;
        const int t_ = isq ? (r & 31) : (r & 63);
        const int b_ = isq ? (r >> 5) : (r >> 6);
        const int mh_ = b_ >> 4, rb = b_ & 15;    // consumer mh, row-in-half
        const long sidx = (long)t_*32768 + mh_*16384
                        + (long)(wslot + (rb >> 2)*16)*16 + (rb & 3)*3 + gate;
        xgi[sidx] = f2b(acc[mt][nt][p] + bias);
      }
    }
  }
}

// ------------------------------------------------------------------ GRU ----
// COLUMN-SPLIT: 12 blocks x 512 threads (8 waves, 2/SIMD -> 256-reg cap).
// Block = (gru, batch-half mh, col-half ch): 16 rows x 128 h-cols.
// Each wave owns 16 h-cols -> ALL 24 weight frags in regs (96 VGPR), no LDS
// weight slots. Per-CU LDS traffic drops 240->~72 b128/step; per-SIMD VALU
// halves. Sibling blocks exchange their 4KB h-half per step through global
// xbuf (double-buffered) with device-scope release/acquire flags
// (correct for any XCD placement; flags zeroed by k_facts each rep).
// Release is placed right after the 4 xbuf stores, BEFORE LDS writes /
// atomics / prefetch, so its vmcnt drain covers only the small L2 stores.
__global__ __launch_bounds__(512, 2) void k_gru(
    const short* __restrict__ q_xg, const short* __restrict__ f_xg,
    const short* __restrict__ b_xg,
    const float* __restrict__ q_whh, const float* __restrict__ q_bhh,
    const float* __restrict__ f_whh, const float* __restrict__ f_bhh,
    const float* __restrict__ b_whh, const float* __restrict__ b_bhh,
    const int* __restrict__ qlens,
    short* __restrict__ xbuf, int* __restrict__ flags,
    float* __restrict__ dout)
{
  __shared__ alignas(16) short hl[2*16*264];   // 16,896 B h double buffer

  const int bid = blockIdx.x;        // 0..11
  const int gru = bid >> 2;          // 0=q, 1=f, 2=b
  const int mh  = (bid >> 1) & 1;    // batch half
  const int ch  = bid & 1;           // column half
  const int pr  = gru*2 + mh;        // sibling-pair id 0..5
  const int tid = threadIdx.x;
  const int l = tid & 63, w = tid >> 6;   // 8 waves
  const int l15 = l & 15, lq = l >> 4;

  const float* whh = (gru == 0) ? q_whh : (gru == 1) ? f_whh : b_whh;
  const float* bhh = (gru == 0) ? q_bhh : (gru == 1) ? f_bhh : b_bhh;
  const short* xgp = (gru == 0) ? q_xg  : (gru == 1) ? f_xg  : b_xg;
  const int T = (gru == 0) ? QL : Sn;

  const int c = ch*128 + w*16 + l15;   // this wave's h-col slice (16 cols)

  // all 24 weight fragments in registers (96 VGPR)
  bf16x8 wf[3][8];
  float bhn = 0.f;
#pragma unroll
  for (int gi = 0; gi < 3; ++gi){
    const int g = gi*256 + c;
    const float* wr = whh + (long)g*Hn;
#pragma unroll
    for (int kk = 0; kk < 8; ++kk){
      const f32x4 f0 = *(const f32x4*)(wr + kk*32 + lq*8);
      const f32x4 f1 = *(const f32x4*)(wr + kk*32 + lq*8 + 4);
      bf16x8 v;
#pragma unroll
      for (int j = 0; j < 4; ++j){ v[j] = f2b(f0[j]); v[4+j] = f2b(f1[j]); }
      wf[gi][kk] = v;
    }
    if (gi == 2) bhn = bhh[g];       // n-gate bhh (r,z folded at producers)
  }

  float hreg[4] = {};
  int qlen_m[4];
#pragma unroll
  for (int p = 0; p < 4; ++p) qlen_m[p] = (gru == 0) ? qlens[mh*16 + lq*4 + p] : -1;

  // xg slot: consumer numbering matches producer (old 16-wave tid = ch*8+w)
  const int so = mh*16384 + (((ch*8 + w)*64 + l))*16;
  float* qdst  = dout + (mh*16 + lq*4)*Hn + c;                      // q_rep
  float* fbase = dout + Bn*Hn + (long)(mh*16 + lq*4)*(Sn*Hn) + c;   // f_out

  // exchange plumbing: per pair, 2 sides x 2 bufs x (16x128) bf16
  short* xw = xbuf + (pr*2 + ch)*4096;         // my side
  const short* xr = xbuf + (pr*2 + (ch^1))*4096;  // peer side
  int* myflag = flags + pr*2 + ch;
  int* pflag  = flags + pr*2 + (ch^1);
  const int xr_row = tid >> 5;                 // peer-read: 8B per thread
  const int xr_c4  = (tid & 31)*4;
  const int pcol   = (ch^1)*128;

  bf16x8 preA0, preA1, preB0, preB1;

#define TOF(TT) ((gru == 2) ? (T - 1 - (TT)) : (TT))
#define LOADP(P0, P1, TI) do{ const short* sb_ = xgp + (long)(TI)*32768 + so; \
    P0 = *(const bf16x8*)(sb_); P1 = *(const bf16x8*)(sb_ + 8); }while(0)

#define EWC(P, IRV, IZV, INV) \
    float hn##P; { \
      const float ir = b2f(IRV), iz = b2f(IZV), in_ = b2f(INV); \
      const float rr = sigm(ir + acc0[P]); \
      const float zz = sigm(iz + acc1[P]); \
      const float nn = tanhx(in_ + rr*acc2[P]); \
      hn##P = (1.0f - zz)*nn + zz*hreg[P]; \
      hreg[P] = hn##P; }

#define GRU_STEP(TT, DOM, DOEX, HIN, HOUT, PR0, PR1, PN0, PN1) do{ \
    f32x4 acc0 = (f32x4){0.f,0.f,0.f,0.f}; \
    f32x4 acc1 = (f32x4){0.f,0.f,0.f,0.f}; \
    f32x4 acc2 = (f32x4){bhn,bhn,bhn,bhn}; \
    if (DOM){ \
      _Pragma("unroll") for (int kk = 0; kk < 8; ++kk){ \
        const bf16x8 a = *(const bf16x8*)&(HIN)[l15*264 + kk*32 + lq*8]; \
        acc0 = mfma16(a, wf[0][kk], acc0); \
        acc1 = mfma16(a, wf[1][kk], acc1); \
        acc2 = mfma16(a, wf[2][kk], acc2); \
      } \
    } \
    const int t_ = TOF(TT); \
    EWC(0, PR0[0], PR0[1], PR0[2]); \
    EWC(1, PR0[3], PR0[4], PR0[5]); \
    EWC(2, PR0[6], PR0[7], PR1[0]); \
    EWC(3, PR1[1], PR1[2], PR1[3]); \
    if (DOEX){ \
      short* xwb = xw + ((TT)&1)*2048 + (lq*4)*128 + (c & 127); \
      xwb[0]   = f2b(hn0); xwb[128] = f2b(hn1); \
      xwb[256] = f2b(hn2); xwb[384] = f2b(hn3); \
      __hip_atomic_store(myflag, (TT)+1, __ATOMIC_RELEASE, __HIP_MEMORY_SCOPE_AGENT); \
      __builtin_amdgcn_sched_barrier(0); \
      LOADP(PN0, PN1, TOF((TT)+1)); \
    } \
    (HOUT)[(lq*4+0)*264 + c] = f2b(hn0); \
    (HOUT)[(lq*4+1)*264 + c] = f2b(hn1); \
    (HOUT)[(lq*4+2)*264 + c] = f2b(hn2); \
    (HOUT)[(lq*4+3)*264 + c] = f2b(hn3); \
    if (gru == 0){ \
      if (t_ == qlen_m[0]-1) qdst[0*Hn] = hn0; \
      if (t_ == qlen_m[1]-1) qdst[1*Hn] = hn1; \
      if (t_ == qlen_m[2]-1) qdst[2*Hn] = hn2; \
      if (t_ == qlen_m[3]-1) qdst[3*Hn] = hn3; \
    } else { \
      atomicAdd(fbase + 0*(Sn*Hn) + t_*Hn, hn0); \
      atomicAdd(fbase + 1*(Sn*Hn) + t_*Hn, hn1); \
      atomicAdd(fbase + 2*(Sn*Hn) + t_*Hn, hn2); \
      atomicAdd(fbase + 3*(Sn*Hn) + t_*Hn, hn3); \
    } \
    if (DOEX){ \
      const int want_ = (TT) + 1; \
      while (__hip_atomic_load(pflag, __ATOMIC_ACQUIRE, __HIP_MEMORY_SCOPE_AGENT) < want_) \
        __builtin_amdgcn_s_sleep(2); \
      const s16x4 pv = *(const s16x4*)&xr[((TT)&1)*2048 + xr_row*128 + xr_c4]; \
      *(s16x4*)&(HOUT)[xr_row*264 + pcol + xr_c4] = pv; \
    } \
    bar_lgkm(); \
  }while(0)

  short* h0 = hl;
  short* h1 = hl + 4224;

  // step 0: h=0 => acc = bias exactly, skip MFMA. Step 0 writes h0 fully
  // (own cols + peer cols via exchange) before step 1 reads it.
  LOADP(preA0, preA1, TOF(0));
  __builtin_amdgcn_sched_barrier(0);
  GRU_STEP(0, 0, 1, h1, h0, preA0, preA1, preB0, preB1);

  for (int tt = 1; tt + 1 < T; tt += 2){
    GRU_STEP(tt,   1, 1, h0, h1, preB0, preB1, preA0, preA1);
    GRU_STEP(tt+1, 1, 1, h1, h0, preA0, preA1, preB0, preB1);
  }
  // tail step T-1 (odd): reads h0, no exchange, no prefetch
  GRU_STEP(T-1, 1, 0, h0, h1, preB0, preB1, preA0, preA1);
#undef TOF
#undef LOADP
#undef EWC
#undef GRU_STEP
}

// -------------------------------------------------------------- launch -----
extern "C" void kernel_launch(void* const* d_in, const int* in_sizes, int n_in,
                              void* d_out, int out_size, void* d_ws, size_t ws_size,
                              hipStream_t stream)
{
  const int*   queries = (const int*)d_in[0];
  const int*   qlens   = (const int*)d_in[1];
  const int*   docs    = (const int*)d_in[2];
  const int*   slens   = (const int*)d_in[3];
  const float* emb     = (const float*)d_in[4];
  const float* q_wih   = (const float*)d_in[5];
  const float* q_whh   = (const float*)d_in[6];
  const float* q_bih   = (const float*)d_in[7];
  const float* q_bhh   = (const float*)d_in[8];
  const float* f_wih   = (const float*)d_in[9];
  const float* f_whh   = (const float*)d_in[10];
  const float* f_bih   = (const float*)d_in[11];
  const float* f_bhh   = (const float*)d_in[12];
  const float* b_wih   = (const float*)d_in[13];
  const float* b_whh   = (const float*)d_in[14];
  const float* b_bih   = (const float*)d_in[15];
  const float* b_bhh   = (const float*)d_in[16];

  // Workspace (13.37 MB):
  //   f_xgi 4MB | b_xgi 4MB | q_xgi 2MB | facts320 1.31MB | wcvt 1.47MB
  //   | xbuf 96KB | flags 48B
  char* wsb = (char*)d_ws;
  short* f_xgi = (short*)(wsb);               // 64*2048*16 bf16 = 4,194,304 B
  short* b_xgi = (short*)(wsb +  4194304);    // 4,194,304 B
  short* q_xgi = (short*)(wsb +  8388608);    // 32*2048*16 bf16 = 2,097,152 B
  short* facts = (short*)(wsb + 10485760);    // 2048*320 bf16 = 1,310,720 B
  short* wcvt  = (short*)(wsb + 11796480);    // 2304*320 bf16 = 1,474,560 B
  short* xbuf  = (short*)(wsb + 13271040);    // 6*2*2*2048 bf16 = 98,304 B
  int*   flags = (int*)  (wsb + 13369344);    // 12 ints

  float* dout = (float*)d_out;                // fp32 output buffer (pre-zeroed)

  k_facts<<<dim3(2048 + 288), 256, 0, stream>>>(docs, slens, emb,
                                                f_wih, b_wih, q_wih,
                                                facts, wcvt, flags, dout);
  k_xg   <<<dim3(16, 12, 3), 256, 0, stream>>>(facts, wcvt, queries, emb,
                                               q_bih, q_bhh, f_bih, f_bhh,
                                               b_bih, b_bhh,
                                               q_xgi, f_xgi, b_xgi);
  k_gru  <<<dim3(12), 512, 0, stream>>>(q_xgi, f_xgi, b_xgi, q_whh, q_bhh,
                                        f_whh, f_bhh, b_whh, b_bhh,
                                        qlens, xbuf, flags, dout);
}

// Round 12
// 481.778 us; speedup vs baseline: 1.2683x; 1.2683x over previous
//
#include <hip/hip_runtime.h>

#define Bn   32
#define QL   32
#define DOCn 2048
#define Sn   64
#define En   300
#define Hn   256

typedef short bf16x8 __attribute__((ext_vector_type(8)));
typedef short s16x4  __attribute__((ext_vector_type(4)));
typedef float f32x4  __attribute__((ext_vector_type(4)));

static __device__ __forceinline__ float b2f(short s){
  unsigned int u = ((unsigned int)(unsigned short)s) << 16;
  float f; __builtin_memcpy(&f, &u, 4); return f;
}
static __device__ __forceinline__ short f2b(float f){
  unsigned int u; __builtin_memcpy(&u, &f, 4);
  u = u + 0x7fffu + ((u >> 16) & 1u);
  return (short)(u >> 16);
}
static __device__ __forceinline__ float sigm(float x){ return 1.0f/(1.0f+__expf(-x)); }
static __device__ __forceinline__ float tanhx(float x){ return 1.0f - 2.0f/(__expf(2.0f*x)+1.0f); }
static __device__ __forceinline__ f32x4 mfma16(bf16x8 a, bf16x8 b, f32x4 c){
  return __builtin_amdgcn_mfma_f32_16x16x32_bf16(a, b, c, 0, 0, 0);
}
// barrier that drains LDS only (no vmcnt(0) store/load drain like __syncthreads)
static __device__ __forceinline__ void bar_lgkm(){
  asm volatile("s_waitcnt lgkmcnt(0)\n\ts_barrier" ::: "memory");
}

// ------------------------------------------------- facts + weight convert --
// Blocks 0..2047: per-(b,s) fact mean-pooling into 320-col zero-padded plane.
//   2-wide unrolled gather (dual accumulators) -> 2 HBM loads in flight.
// Blocks 2048..2335: fp32->bf16 wih conversion (8 rows each, z-order f,b,q).
// Also emits num_facts (s==0, ballot).
__global__ __launch_bounds__(256) void k_facts(
    const int* __restrict__ docs, const int* __restrict__ slens,
    const float* __restrict__ emb,
    const float* __restrict__ f_wih, const float* __restrict__ b_wih,
    const float* __restrict__ q_wih,
    short* __restrict__ facts, short* __restrict__ wcvt,
    float* __restrict__ dout)
{
  const int tid = threadIdx.x;

  if (blockIdx.x >= 2048){
    // ------------------------------------------------------- weight cvt ----
    const int rg0 = (blockIdx.x - 2048)*8;          // 8 rows per block
#pragma unroll
    for (int rr = 0; rr < 8; ++rr){
      const int rg = rg0 + rr;                      // 0..2303
      const int z = rg / 768, g = rg % 768;
      const float* src = ((z == 0) ? f_wih : (z == 1) ? b_wih : q_wih) + (long)g*En;
      short* dst = wcvt + (long)rg*320;
      for (int c = tid; c < 320; c += 256)
        dst[c] = (c < En) ? f2b(src[c]) : (short)0;
    }
    return;
  }

  // ---------------------------------------------------------------- facts --
  __shared__ int pref[2*Sn];
  const int blk = blockIdx.x;
  const int b = blk >> 6, s = blk & 63;
  if (tid < Sn){                       // wave 0: parallel prefix over lens
    const int v = slens[b*Sn + tid];
    int x = v;
#pragma unroll
    for (int d = 1; d < 64; d <<= 1){
      const int y = __shfl_up(x, d, 64);
      if (tid >= d) x += y;
    }
    pref[tid] = x - v;                 // exclusive prefix
    pref[Sn + tid] = v;
    if (s == 0){                       // num_facts once per b
      const unsigned long long m = __ballot(v > 0);
      if (tid == 0) dout[Bn*Hn + (long)Bn*Sn*Hn + b] = (float)__popcll(m);
    }
  }
  __syncthreads();
  const int off = pref[s];
  const int len = pref[Sn + s];
  const bool act = tid < 150;
  float a0 = 0.f, a1 = 0.f, b0 = 0.f, b1 = 0.f;
  const int* dtok = docs + b*DOCn + off;
  int tkA = (0 < len) ? dtok[0] : 0;
  int tkB = (1 < len) ? dtok[1] : 0;
  int i = 0;
  for (; i + 2 <= len; i += 2){
    const int tkA2 = (i+2 < len) ? dtok[i+2] : 0;
    const int tkB2 = (i+3 < len) ? dtok[i+3] : 0;
    if (act){
      const float2 va = *(const float2*)(emb + (long)tkA*En + 2*tid);
      const float2 vb = *(const float2*)(emb + (long)tkB*En + 2*tid);
      a0 += va.x; a1 += va.y; b0 += vb.x; b1 += vb.y;
    }
    tkA = tkA2; tkB = tkB2;
  }
  if (i < len && act){
    const float2 va = *(const float2*)(emb + (long)tkA*En + 2*tid);
    a0 += va.x; a1 += va.y;
  }
  a0 += b0; a1 += b1;
  const float inv = 1.0f / (float)(len > 0 ? len : 1);
  short* frow = facts + ((long)b*Sn + s)*320;        // 320-col padded plane
  if (act){
    frow[2*tid]   = f2b(a0*inv);
    frow[2*tid+1] = f2b(a1*inv);
  } else if (tid < 160){
    const int e = tid - 150;
    frow[300 + 2*e] = 0; frow[301 + 2*e] = 0;        // zero pad 300..319
  }
}

// -------------------------------------------------------- unified xg GEMM --
// 128-row tiles. z=0 -> f (A=facts), z=1 -> b (A=facts), z=2 -> q (A=emb
// gather, bm<8). Weights pre-converted bf16 (wcvt, 320-padded).
// OUTPUT: tid-ordered plane [t][2048 slots][16 shorts]: slot = mh*1024 + tid
// of the consuming k_gru thread; within a slot, short idx = p*3 + gate
// (12 used + 4 pad). Gives k_gru a 2-instr fully-coalesced 32B load.
// bhh folded into bias for r,z gates.
__global__ __launch_bounds__(256) void k_xg(
    const short* __restrict__ facts, const short* __restrict__ wcvt,
    const int* __restrict__ queries, const float* __restrict__ emb,
    const float* __restrict__ q_bih, const float* __restrict__ q_bhh,
    const float* __restrict__ f_bih, const float* __restrict__ f_bhh,
    const float* __restrict__ b_bih, const float* __restrict__ b_bhh,
    short* __restrict__ q_xgi, short* __restrict__ f_xgi,
    short* __restrict__ b_xgi)
{
  const int z = blockIdx.z;
  const int bm = blockIdx.x, bn = blockIdx.y;
  const bool isq = (z == 2);
  if (isq && bm >= 8) return;          // q has 1024 rows only

  const float* bih = (z == 0) ? f_bih : (z == 1) ? b_bih : q_bih;
  const float* bhh = (z == 0) ? f_bhh : (z == 1) ? b_bhh : q_bhh;
  short*       xgi = (z == 0) ? f_xgi : (z == 1) ? b_xgi : q_xgi;

  __shared__ alignas(16) short Al[2][128][40];
  const int tid = threadIdx.x;
  const int l = tid & 63, w = tid >> 6;
  const int wm = w & 1, wn = w >> 1;
  const int l15 = l & 15, lq = l >> 4;
  const int ak8 = w*8;

  // weight fragments: 20 x bf16x8 straight loads (no cvt, no tails)
  bf16x8 bfr[2][10];
#pragma unroll
  for (int nt = 0; nt < 2; ++nt){
    const int g = bn*64 + wn*32 + nt*16 + l15;
    const short* wr = wcvt + ((long)z*768 + g)*320;
#pragma unroll
    for (int kk = 0; kk < 10; ++kk)
      bfr[nt][kk] = *(const bf16x8*)&wr[kk*32 + lq*8];
  }

  // A sources: two rows per thread (l and 64+l)
  const short* asrc_f0 = nullptr; const short* asrc_f1 = nullptr;
  const float* asrc_q0 = nullptr; const float* asrc_q1 = nullptr;
  if (isq){
    asrc_q0 = emb + (long)queries[bm*128 + l]*En;
    asrc_q1 = emb + (long)queries[bm*128 + 64 + l]*En;
  } else {
    asrc_f0 = facts + (long)(bm*128 + l)*320;
    asrc_f1 = facts + (long)(bm*128 + 64 + l)*320;
  }

  bf16x8 va0, va1;
#define LDA_(KK) do{ const int k0_ = (KK)*32 + ak8; \
    if (!isq){ \
      va0 = *(const bf16x8*)(asrc_f0 + k0_); \
      va1 = *(const bf16x8*)(asrc_f1 + k0_); \
    } else if (k0_ + 7 < En){ \
      const f32x4 p0 = *(const f32x4*)(asrc_q0+k0_), p1 = *(const f32x4*)(asrc_q0+k0_+4); \
      const f32x4 p2 = *(const f32x4*)(asrc_q1+k0_), p3 = *(const f32x4*)(asrc_q1+k0_+4); \
      _Pragma("unroll") for (int j = 0; j < 4; ++j){ \
        va0[j] = f2b(p0[j]); va0[4+j] = f2b(p1[j]); \
        va1[j] = f2b(p2[j]); va1[4+j] = f2b(p3[j]); } \
    } else { \
      _Pragma("unroll") for (int j = 0; j < 8; ++j){ const int k_ = k0_ + j; \
        va0[j] = (k_ < En) ? f2b(asrc_q0[k_]) : (short)0; \
        va1[j] = (k_ < En) ? f2b(asrc_q1[k_]) : (short)0; } \
    } }while(0)
#define STA_(BUF) do{ *(bf16x8*)&Al[BUF][l][ak8] = va0; \
    *(bf16x8*)&Al[BUF][64 + l][ak8] = va1; }while(0)

  LDA_(0); STA_(0);
  __syncthreads();

  f32x4 acc[4][2] = {};
#pragma unroll
  for (int kk = 0; kk < 10; ++kk){
    if (kk < 9) LDA_(kk+1);
#pragma unroll
    for (int mt = 0; mt < 4; ++mt){
      bf16x8 a = *(const bf16x8*)&Al[kk&1][wm*64 + mt*16 + l15][lq*8];
      acc[mt][0] = mfma16(a, bfr[0][kk], acc[mt][0]);
      acc[mt][1] = mfma16(a, bfr[1][kk], acc[mt][1]);
    }
    if (kk < 9) STA_((kk+1)&1);
    __syncthreads();
  }
#undef LDA_
#undef STA_

  // epilogue: scatter into tid-ordered consumption layout
#pragma unroll
  for (int nt = 0; nt < 2; ++nt){
    const int cg = bn*64 + wn*32 + nt*16 + l15;   // 0..767
    float bias = bih[cg];
    if (cg < 512) bias += bhh[cg];                // fold bhh for r,z gates
    const int gate = cg >> 8, hc = cg & 255;
    const int wslot = (hc >> 4)*64 + (hc & 15);   // consumer w'*64 + l15'
#pragma unroll
    for (int mt = 0; mt < 4; ++mt){
      const int r0 = bm*128 + wm*64 + mt*16 + lq*4;
#pragma unroll
      for (int p = 0; p < 4; ++p){
        const int r = r0 + p;
        const int t_ = isq ? (r & 31) : (r & 63);
        const int b_ = isq ? (r >> 5) : (r >> 6);
        const int mh_ = b_ >> 4, rb = b_ & 15;    // consumer mh, row-in-half
        const long sidx = (long)t_*32768 + mh_*16384
                        + (long)(wslot + (rb >> 2)*16)*16 + (rb & 3)*3 + gate;
        xgi[sidx] = f2b(acc[mt][nt][p] + bias);
      }
    }
  }
}

// ------------------------------------------------------------------ GRU ----
// EXACT round-8/10 structure (best measured: 255.6us, reconfirmed). 6 blocks
// x 1024 threads (16 waves, 4/SIMD). Weights: 17 frags in regs + 7 in
// per-tid LDS slots. xg loads: tid-ordered 32B slot -> 2 coalesced b128
// loads, double-buffered, addresses recomputed per step from the induction
// var (round-9 lesson: loop-carried pointers serialize the prefetch address
// chain). Round-11 lesson: column-split across blocks with per-step global
// release/acquire exchange costs ~5K cy/step (cross-XCD L2 writeback +
// spin-wait) -- far more than the register/LDS win. This recurrence is
// bound to one CU per (gru, batch-half); ~9.6K cy/step is its plateau.
// lgkm-only barriers; bhh(r,z) folded at producers; f/b h-states straight
// to dout via fp32 atomicAdd (2 commutative adds, dout pre-zeroed).
__global__ __launch_bounds__(1024) void k_gru(
    const short* __restrict__ q_xg, const short* __restrict__ f_xg,
    const short* __restrict__ b_xg,
    const float* __restrict__ q_whh, const float* __restrict__ q_bhh,
    const float* __restrict__ f_whh, const float* __restrict__ f_bhh,
    const float* __restrict__ b_whh, const float* __restrict__ b_bhh,
    const int* __restrict__ qlens,
    float* __restrict__ dout)
{
  __shared__ alignas(16) short hl[2*16*264];   // 16,896 B h double buffer
  __shared__ alignas(16) short wl[7*1024*8];   // 114,688 B weight frag slices

  const int gru = blockIdx.x >> 1;   // 0=q, 1=f, 2=b
  const int mh  = blockIdx.x & 1;
  const int tid = threadIdx.x;
  const int l = tid & 63, w = tid >> 6;   // 16 waves
  const int l15 = l & 15, lq = l >> 4;

  const float* whh = (gru == 0) ? q_whh : (gru == 1) ? f_whh : b_whh;
  const float* bhh = (gru == 0) ? q_bhh : (gru == 1) ? f_bhh : b_bhh;
  const short* xgp = (gru == 0) ? q_xg  : (gru == 1) ? f_xg  : b_xg;
  const int T = (gru == 0) ? QL : Sn;

  const int c = w*16 + l15;          // this wave's gate column slice

  // weight fragment load: LDS set = {kk=6,7 all gates} U {kk=5, gate 2}
  bf16x8 wf[3][6];                   // [2][5] unused -> 17 live frags = 68 VGPR
  float bhn = 0.f;
#pragma unroll
  for (int gi = 0; gi < 3; ++gi){
    const int g = gi*256 + c;
    const float* wr = whh + (long)g*Hn;
#pragma unroll
    for (int kk = 0; kk < 8; ++kk){
      const f32x4 f0 = *(const f32x4*)(wr + kk*32 + lq*8);
      const f32x4 f1 = *(const f32x4*)(wr + kk*32 + lq*8 + 4);
      bf16x8 v;
#pragma unroll
      for (int j = 0; j < 4; ++j){ v[j] = f2b(f0[j]); v[4+j] = f2b(f1[j]); }
      if (kk < 5 || (kk == 5 && gi < 2)) wf[gi][kk] = v;
      else if (kk == 5)                  *(bf16x8*)&wl[(6*1024 + tid)*8] = v;
      else                               *(bf16x8*)&wl[(((kk-6)*3 + gi)*1024 + tid)*8] = v;
    }
    if (gi == 2) bhn = bhh[g];       // n-gate bhh (r,z folded at producers)
  }

  float hreg[4] = {};
  int qlen_m[4];
#pragma unroll
  for (int p = 0; p < 4; ++p) qlen_m[p] = (gru == 0) ? qlens[mh*16 + lq*4 + p] : -1;

  const int so = mh*16384 + tid*16;            // tid-ordered xg slot (shorts)
  float* qdst  = dout + (mh*16 + lq*4)*Hn + c;                      // q_rep
  float* fbase = dout + Bn*Hn + (long)(mh*16 + lq*4)*(Sn*Hn) + c;   // f_out

  bf16x8 preA0, preA1, preB0, preB1;

#define TOF(TT) ((gru == 2) ? (T - 1 - (TT)) : (TT))
#define LOADP(P0, P1, TI) do{ const short* sb_ = xgp + (long)(TI)*32768 + so; \
    P0 = *(const bf16x8*)(sb_); P1 = *(const bf16x8*)(sb_ + 8); }while(0)

#define GRU_EW(P, HOUT, IRV, IZV, INV) do{ \
      const float ir = b2f(IRV), iz = b2f(IZV), in_ = b2f(INV); \
      const float rr = sigm(ir + acc0[P]); \
      const float zz = sigm(iz + acc1[P]); \
      const float nn = tanhx(in_ + rr*acc2[P]); \
      const float hn = (1.0f - zz)*nn + zz*hreg[P]; \
      hreg[P] = hn; \
      (HOUT)[(lq*4 + P)*264 + c] = f2b(hn); \
      if (gru == 0){ if (t_ == qlen_m[P] - 1) qdst[P*Hn] = hn; } \
      else { atomicAdd(fbase + P*(Sn*Hn) + t_*Hn, hn); } \
    }while(0)

#define GRU_STEP(TT, DOM, HIN, HOUT, PR0, PR1) do{ \
    f32x4 acc0 = (f32x4){0.f,0.f,0.f,0.f}; \
    f32x4 acc1 = (f32x4){0.f,0.f,0.f,0.f}; \
    f32x4 acc2 = (f32x4){bhn,bhn,bhn,bhn}; \
    if (DOM){ \
      _Pragma("unroll") for (int kk = 0; kk < 5; ++kk){ \
        const bf16x8 a = *(const bf16x8*)&(HIN)[l15*264 + kk*32 + lq*8]; \
        acc0 = mfma16(a, wf[0][kk], acc0); \
        acc1 = mfma16(a, wf[1][kk], acc1); \
        acc2 = mfma16(a, wf[2][kk], acc2); \
      } \
      { const bf16x8 a = *(const bf16x8*)&(HIN)[l15*264 + 5*32 + lq*8]; \
        const bf16x8 w2 = *(const bf16x8*)&wl[(6*1024 + tid)*8]; \
        acc0 = mfma16(a, wf[0][5], acc0); \
        acc1 = mfma16(a, wf[1][5], acc1); \
        acc2 = mfma16(a, w2, acc2); } \
      { const bf16x8 a = *(const bf16x8*)&(HIN)[l15*264 + 6*32 + lq*8]; \
        const bf16x8 w0 = *(const bf16x8*)&wl[(0*1024 + tid)*8]; \
        const bf16x8 w1 = *(const bf16x8*)&wl[(1*1024 + tid)*8]; \
        const bf16x8 w2 = *(const bf16x8*)&wl[(2*1024 + tid)*8]; \
        acc0 = mfma16(a, w0, acc0); \
        acc1 = mfma16(a, w1, acc1); \
        acc2 = mfma16(a, w2, acc2); } \
      { const bf16x8 a = *(const bf16x8*)&(HIN)[l15*264 + 7*32 + lq*8]; \
        const bf16x8 w0 = *(const bf16x8*)&wl[(3*1024 + tid)*8]; \
        const bf16x8 w1 = *(const bf16x8*)&wl[(4*1024 + tid)*8]; \
        const bf16x8 w2 = *(const bf16x8*)&wl[(5*1024 + tid)*8]; \
        acc0 = mfma16(a, w0, acc0); \
        acc1 = mfma16(a, w1, acc1); \
        acc2 = mfma16(a, w2, acc2); } \
    } \
    const int t_ = TOF(TT); \
    GRU_EW(0, HOUT, PR0[0], PR0[1], PR0[2]); \
    GRU_EW(1, HOUT, PR0[3], PR0[4], PR0[5]); \
    GRU_EW(2, HOUT, PR0[6], PR0[7], PR1[0]); \
    GRU_EW(3, HOUT, PR1[1], PR1[2], PR1[3]); \
  }while(0)

  short* h0 = hl;
  short* h1 = hl + 4224;

  // step 0: h=0 => acc = bias exactly, skip MFMA; h1 never read at step 0,
  // h0 fully written by step 0 before step 1 reads it -> no zero-init needed.
  LOADP(preA0, preA1, TOF(0));
  LOADP(preB0, preB1, TOF(1));
  __builtin_amdgcn_sched_barrier(0);
  GRU_STEP(0, 0, h1, h0, preA0, preA1);      // writes h0
  bar_lgkm();
  LOADP(preA0, preA1, TOF(2));
  __builtin_amdgcn_sched_barrier(0);
  GRU_STEP(1, 1, h0, h1, preB0, preB1);      // reads h0, writes h1
  bar_lgkm();

  for (int tt = 2; tt < T; tt += 2){
    const int tiB = (tt+1 < T) ? (tt+1) : (T-1);
    LOADP(preB0, preB1, TOF(tiB));
    __builtin_amdgcn_sched_barrier(0);
    GRU_STEP(tt, 1, h1, h0, preA0, preA1);   // reads h1, writes h0
    bar_lgkm();
    const int tiA = (tt+2 < T) ? (tt+2) : (T-1);
    LOADP(preA0, preA1, TOF(tiA));
    __builtin_amdgcn_sched_barrier(0);
    GRU_STEP(tt+1, 1, h0, h1, preB0, preB1); // reads h0, writes h1
    bar_lgkm();
  }
#undef TOF
#undef LOADP
#undef GRU_EW
#undef GRU_STEP
}

// -------------------------------------------------------------- launch -----
extern "C" void kernel_launch(void* const* d_in, const int* in_sizes, int n_in,
                              void* d_out, int out_size, void* d_ws, size_t ws_size,
                              hipStream_t stream)
{
  const int*   queries = (const int*)d_in[0];
  const int*   qlens   = (const int*)d_in[1];
  const int*   docs    = (const int*)d_in[2];
  const int*   slens   = (const int*)d_in[3];
  const float* emb     = (const float*)d_in[4];
  const float* q_wih   = (const float*)d_in[5];
  const float* q_whh   = (const float*)d_in[6];
  const float* q_bih   = (const float*)d_in[7];
  const float* q_bhh   = (const float*)d_in[8];
  const float* f_wih   = (const float*)d_in[9];
  const float* f_whh   = (const float*)d_in[10];
  const float* f_bih   = (const float*)d_in[11];
  const float* f_bhh   = (const float*)d_in[12];
  const float* b_wih   = (const float*)d_in[13];
  const float* b_whh   = (const float*)d_in[14];
  const float* b_bih   = (const float*)d_in[15];
  const float* b_bhh   = (const float*)d_in[16];

  // Workspace (13.27 MB):
  //   f_xgi 4MB | b_xgi 4MB | q_xgi 2MB | facts320 1.31MB | wcvt 1.47MB
  char* wsb = (char*)d_ws;
  short* f_xgi = (short*)(wsb);               // 64*2048*16 bf16 = 4,194,304 B
  short* b_xgi = (short*)(wsb +  4194304);    // 4,194,304 B
  short* q_xgi = (short*)(wsb +  8388608);    // 32*2048*16 bf16 = 2,097,152 B
  short* facts = (short*)(wsb + 10485760);    // 2048*320 bf16 = 1,310,720 B
  short* wcvt  = (short*)(wsb + 11796480);    // 2304*320 bf16 = 1,474,560 B

  float* dout = (float*)d_out;                // fp32 output buffer (pre-zeroed)

  k_facts<<<dim3(2048 + 288), 256, 0, stream>>>(docs, slens, emb,
                                                f_wih, b_wih, q_wih,
                                                facts, wcvt, dout);
  k_xg   <<<dim3(16, 12, 3), 256, 0, stream>>>(facts, wcvt, queries, emb,
                                               q_bih, q_bhh, f_bih, f_bhh,
                                               b_bih, b_bhh,
                                               q_xgi, f_xgi, b_xgi);
  k_gru  <<<dim3(6), 1024, 0, stream>>>(q_xgi, f_xgi, b_xgi, q_whh, q_bhh,
                                        f_whh, f_bhh, b_whh, b_bhh,
                                        qlens, dout);
}